// Round 5
// baseline (182.327 us; speedup 1.0000x reference)
//
#include <hip/hip_runtime.h>
#include <hip/hip_bf16.h>

// TriplesDistances: B=16, N=512, A=1024
// positions: float32 [B,N,3]; neighbors_j/k: int32 [B,N,A]; out: float32,
// (r_ij | r_ik | r_jk) each [B,N,A] concatenated flat.
//
// R3 passed at bench dur_us=157.7; kernel dispatch <58 us (absent from top-5,
// which is headed by 58-60us/402MB poison fills at ~6.9 TB/s). Kernel HBM
// floor: 67 MB idx + 100 MB out = 167 MB => ~24 us.
//
// R4: cut LDS-gather cost — float4-padded LDS (1x ds_read_b128 per atom vs
// 3x ds_read_b32), 2 rows/block + 8 triples/thread (half the staging, more
// ILP), nontemporal for streamed idx/out.

namespace {
constexpr int kB = 16;
constexpr int kN = 512;
constexpr int kA = 1024;
constexpr long long kBNA = (long long)kB * kN * kA;  // 8,388,608

typedef int   iv4 __attribute__((ext_vector_type(4)));
typedef float fv4 __attribute__((ext_vector_type(4)));
}  // namespace

__global__ __launch_bounds__(256) void TriplesDistances_kernel(
    const float* __restrict__ pos,   // f32 [B*N*3]
    const int* __restrict__ nj,      // int32 [B*N*A]
    const int* __restrict__ nk,      // int32 [B*N*A]
    float* __restrict__ out)         // f32 [3*B*N*A]
{
    __shared__ fv4 spos[kN];  // 8 KB, float4-padded positions of this batch

    const int bid = blockIdx.x;        // 0..4095
    const int b   = bid >> 8;          // batch
    const int n0  = (bid & 255) << 1;  // first of 2 rows
    const int tid = threadIdx.x;

    // Stage batch-b positions: 1536 packed floats -> padded float4 layout.
    // 6 coalesced dwords/thread; scatter addr = e + e/3 dwords (<=2-way bank).
    {
        const float* p = pos + (size_t)b * (kN * 3);
#pragma unroll
        for (int t = 0; t < 6; ++t) {
            const int e = tid + t * 256;
            const int a = e / 3;         // magic-mul, no HW div
            const int c = e - a * 3;
            ((float*)&spos[a])[c] = p[e];
        }
    }
    __syncthreads();

    const int row  = n0 + (tid >> 7);   // waves 0,1 -> row n0; waves 2,3 -> n0+1
    const int lane = tid & 127;
    const fv4 pi = spos[row];
    const float xi = pi.x, yi = pi.y, zi = pi.z;

    const long long base = ((long long)b * kN + row) * kA + lane * 8;  // 32B-aligned

    const iv4* jp = (const iv4*)(nj + base);
    const iv4* kp = (const iv4*)(nk + base);
    const iv4 ja = __builtin_nontemporal_load(jp);
    const iv4 jb = __builtin_nontemporal_load(jp + 1);
    const iv4 ka = __builtin_nontemporal_load(kp);
    const iv4 kb = __builtin_nontemporal_load(kp + 1);

    const int js[8] = {ja.x, ja.y, ja.z, ja.w, jb.x, jb.y, jb.z, jb.w};
    const int ks[8] = {ka.x, ka.y, ka.z, ka.w, kb.x, kb.y, kb.z, kb.w};

    float rij[8], rik[8], rjk[8];
#pragma unroll
    for (int t = 0; t < 8; ++t) {
        const fv4 pj = spos[js[t]];   // 1x ds_read_b128
        const fv4 pk = spos[ks[t]];   // 1x ds_read_b128

        // safe_norm: sqrtf(0)=0 matches where(s>0, sqrt(s), 0)
        float dx = pj.x - xi, dy = pj.y - yi, dz = pj.z - zi;
        rij[t] = sqrtf(dx * dx + dy * dy + dz * dz);

        dx = pk.x - xi; dy = pk.y - yi; dz = pk.z - zi;
        rik[t] = sqrtf(dx * dx + dy * dy + dz * dz);

        dx = pj.x - pk.x; dy = pj.y - pk.y; dz = pj.z - pk.z;
        rjk[t] = sqrtf(dx * dx + dy * dy + dz * dz);
    }

    // 2x 16B nontemporal stores per plane (streamed, never re-read).
#pragma unroll
    for (int half = 0; half < 2; ++half) {
        const int o = half * 4;
        fv4 v;
        v.x = rij[o]; v.y = rij[o + 1]; v.z = rij[o + 2]; v.w = rij[o + 3];
        __builtin_nontemporal_store(v, (fv4*)(out + base) + half);
        v.x = rik[o]; v.y = rik[o + 1]; v.z = rik[o + 2]; v.w = rik[o + 3];
        __builtin_nontemporal_store(v, (fv4*)(out + kBNA + base) + half);
        v.x = rjk[o]; v.y = rjk[o + 1]; v.z = rjk[o + 2]; v.w = rjk[o + 3];
        __builtin_nontemporal_store(v, (fv4*)(out + 2 * kBNA + base) + half);
    }
}

extern "C" void kernel_launch(void* const* d_in, const int* in_sizes, int n_in,
                              void* d_out, int out_size, void* d_ws, size_t ws_size,
                              hipStream_t stream) {
    const float* pos = (const float*)d_in[0];
    const int* nj = (const int*)d_in[1];
    const int* nk = (const int*)d_in[2];
    float* out = (float*)d_out;

    // 2 rows per block: grid = B * N/2 = 4096 blocks, 256 threads.
    TriplesDistances_kernel<<<kB * (kN / 2), 256, 0, stream>>>(pos, nj, nk, out);
}

// Round 6
// 158.249 us; speedup vs baseline: 1.1522x; 1.1522x over previous
//
#include <hip/hip_runtime.h>
#include <hip/hip_bf16.h>

// TriplesDistances: B=16, N=512, A=1024
// positions: float32 [B,N,3]; neighbors_j/k: int32 [B,N,A]; out: float32,
// (r_ij | r_ik | r_jk) each [B,N,A] concatenated flat.
//
// R4 post-mortem: nontemporal stores DOUBLED HBM write traffic (WRITE_SIZE
// 185 MB vs 100 MB out) — the harness poison-fill leaves out dirty in L2;
// nt stores bypass those lines, so the kernel pays both its own writes AND
// the poison evictions. Kernel regressed to 75 us @ 3 TB/s. R5: revert all
// nontemporal (plain stores overwrite dirty lines in L2). Keep float4 LDS
// (1x ds_read_b128/atom), 2 rows/block, 8 triples/thread.

namespace {
constexpr int kB = 16;
constexpr int kN = 512;
constexpr int kA = 1024;
constexpr long long kBNA = (long long)kB * kN * kA;  // 8,388,608

typedef int   iv4 __attribute__((ext_vector_type(4)));
typedef float fv4 __attribute__((ext_vector_type(4)));
}  // namespace

__global__ __launch_bounds__(256) void TriplesDistances_kernel(
    const float* __restrict__ pos,   // f32 [B*N*3]
    const int* __restrict__ nj,      // int32 [B*N*A]
    const int* __restrict__ nk,      // int32 [B*N*A]
    float* __restrict__ out)         // f32 [3*B*N*A]
{
    __shared__ fv4 spos[kN];  // 8 KB, float4-padded positions of this batch

    const int bid = blockIdx.x;        // 0..4095
    const int b   = bid >> 8;          // batch
    const int n0  = (bid & 255) << 1;  // first of 2 rows
    const int tid = threadIdx.x;

    // Stage batch-b positions: 1536 packed floats -> padded float4 layout.
    {
        const float* p = pos + (size_t)b * (kN * 3);
#pragma unroll
        for (int t = 0; t < 6; ++t) {
            const int e = tid + t * 256;
            const int a = e / 3;         // magic-mul, no HW div
            const int c = e - a * 3;
            ((float*)&spos[a])[c] = p[e];
        }
    }
    __syncthreads();

    const int row  = n0 + (tid >> 7);   // waves 0,1 -> row n0; waves 2,3 -> n0+1
    const int lane = tid & 127;
    const fv4 pi = spos[row];
    const float xi = pi.x, yi = pi.y, zi = pi.z;

    const long long base = ((long long)b * kN + row) * kA + lane * 8;  // 32B-aligned

    const iv4* jp = (const iv4*)(nj + base);
    const iv4* kp = (const iv4*)(nk + base);
    const iv4 ja = jp[0];
    const iv4 jb = jp[1];
    const iv4 ka = kp[0];
    const iv4 kb = kp[1];

    const int js[8] = {ja.x, ja.y, ja.z, ja.w, jb.x, jb.y, jb.z, jb.w};
    const int ks[8] = {ka.x, ka.y, ka.z, ka.w, kb.x, kb.y, kb.z, kb.w};

    float rij[8], rik[8], rjk[8];
#pragma unroll
    for (int t = 0; t < 8; ++t) {
        const fv4 pj = spos[js[t]];   // 1x ds_read_b128
        const fv4 pk = spos[ks[t]];   // 1x ds_read_b128

        // safe_norm: sqrtf(0)=0 matches where(s>0, sqrt(s), 0)
        float dx = pj.x - xi, dy = pj.y - yi, dz = pj.z - zi;
        rij[t] = sqrtf(dx * dx + dy * dy + dz * dz);

        dx = pk.x - xi; dy = pk.y - yi; dz = pk.z - zi;
        rik[t] = sqrtf(dx * dx + dy * dy + dz * dz);

        dx = pj.x - pk.x; dy = pj.y - pk.y; dz = pj.z - pk.z;
        rjk[t] = sqrtf(dx * dx + dy * dy + dz * dz);
    }

    // 2x 16B plain stores per plane (overwrite poison-dirty L2 lines in place).
#pragma unroll
    for (int half = 0; half < 2; ++half) {
        const int o = half * 4;
        fv4 v;
        v.x = rij[o]; v.y = rij[o + 1]; v.z = rij[o + 2]; v.w = rij[o + 3];
        ((fv4*)(out + base))[half] = v;
        v.x = rik[o]; v.y = rik[o + 1]; v.z = rik[o + 2]; v.w = rik[o + 3];
        ((fv4*)(out + kBNA + base))[half] = v;
        v.x = rjk[o]; v.y = rjk[o + 1]; v.z = rjk[o + 2]; v.w = rjk[o + 3];
        ((fv4*)(out + 2 * kBNA + base))[half] = v;
    }
}

extern "C" void kernel_launch(void* const* d_in, const int* in_sizes, int n_in,
                              void* d_out, int out_size, void* d_ws, size_t ws_size,
                              hipStream_t stream) {
    const float* pos = (const float*)d_in[0];
    const int* nj = (const int*)d_in[1];
    const int* nk = (const int*)d_in[2];
    float* out = (float*)d_out;

    // 2 rows per block: grid = B * N/2 = 4096 blocks, 256 threads.
    TriplesDistances_kernel<<<kB * (kN / 2), 256, 0, stream>>>(pos, nj, nk, out);
}

// Round 7
// 156.295 us; speedup vs baseline: 1.1666x; 1.0125x over previous
//
#include <hip/hip_runtime.h>
#include <hip/hip_bf16.h>

// TriplesDistances: B=16, N=512, A=1024
// positions: float32 [B,N,3]; neighbors_j/k: int32 [B,N,A]; out: float32,
// (r_ij | r_ik | r_jk) each [B,N,A] concatenated flat.
//
// R5 post-mortem: kernel ~50us (bench-delta decomposition), but cycle budget
// says ~latency-bound, not BW-bound (mixed-stream HBM can do 6.3+ TB/s, we
// achieve ~2.7). R6: perfect per-instruction coalescing (lane*4 interleave,
// 1 KB per iv4/fv4 instruction), one row per wave (4 rows/block, grid 2048),
// 16 elems/thread for ILP, launch_bounds(256,8) for 32 waves/CU residency.

namespace {
constexpr int kB = 16;
constexpr int kN = 512;
constexpr int kA = 1024;
constexpr long long kBNA = (long long)kB * kN * kA;  // 8,388,608

typedef int   iv4 __attribute__((ext_vector_type(4)));
typedef float fv4 __attribute__((ext_vector_type(4)));
}  // namespace

__global__ __launch_bounds__(256, 8) void TriplesDistances_kernel(
    const float* __restrict__ pos,   // f32 [B*N*3]
    const int* __restrict__ nj,      // int32 [B*N*A]
    const int* __restrict__ nk,      // int32 [B*N*A]
    float* __restrict__ out)         // f32 [3*B*N*A]
{
    __shared__ fv4 spos[kN];  // 8 KB, float4-padded positions of this batch

    const int bid = blockIdx.x;        // 0..2047
    const int b   = bid >> 7;          // batch (128 blocks per batch)
    const int n0  = (bid & 127) << 2;  // first of 4 rows
    const int tid = threadIdx.x;

    // Stage batch-b positions: 1536 packed floats -> padded float4 layout.
    {
        const float* p = pos + (size_t)b * (kN * 3);
#pragma unroll
        for (int t = 0; t < 6; ++t) {
            const int e = tid + t * 256;
            const int a = e / 3;         // magic-mul, no HW div
            const int c = e - a * 3;
            ((float*)&spos[a])[c] = p[e];
        }
    }
    __syncthreads();

    const int wave = tid >> 6;          // 0..3 -> row n0+wave
    const int lane = tid & 63;
    const int row  = n0 + wave;
    const fv4 pi = spos[row];
    const float xi = pi.x, yi = pi.y, zi = pi.z;

    // Wave owns the full 1024-element row; 4 chunks of 256 elements.
    // Thread offset lane*4 => every iv4 load / fv4 store is 1 KB coalesced.
    const long long rowbase = ((long long)b * kN + row) * kA;

#pragma unroll
    for (int c = 0; c < 4; ++c) {
        const long long off = rowbase + c * 256 + lane * 4;

        const iv4 j4 = *(const iv4*)(nj + off);
        const iv4 k4 = *(const iv4*)(nk + off);
        const int js[4] = {j4.x, j4.y, j4.z, j4.w};
        const int ks[4] = {k4.x, k4.y, k4.z, k4.w};

        fv4 vij, vik, vjk;
        float* rij = (float*)&vij;
        float* rik = (float*)&vik;
        float* rjk = (float*)&vjk;
#pragma unroll
        for (int t = 0; t < 4; ++t) {
            const fv4 pj = spos[js[t]];   // 1x ds_read_b128
            const fv4 pk = spos[ks[t]];   // 1x ds_read_b128

            // safe_norm: sqrtf(0)=0 matches where(s>0, sqrt(s), 0)
            float dx = pj.x - xi, dy = pj.y - yi, dz = pj.z - zi;
            rij[t] = sqrtf(dx * dx + dy * dy + dz * dz);

            dx = pk.x - xi; dy = pk.y - yi; dz = pk.z - zi;
            rik[t] = sqrtf(dx * dx + dy * dy + dz * dz);

            dx = pj.x - pk.x; dy = pj.y - pk.y; dz = pj.z - pk.z;
            rjk[t] = sqrtf(dx * dx + dy * dy + dz * dz);
        }

        // 1 KB coalesced plain stores (overwrite poison-dirty L2 lines).
        *(fv4*)(out + off)            = vij;
        *(fv4*)(out + kBNA + off)     = vik;
        *(fv4*)(out + 2 * kBNA + off) = vjk;
    }
}

extern "C" void kernel_launch(void* const* d_in, const int* in_sizes, int n_in,
                              void* d_out, int out_size, void* d_ws, size_t ws_size,
                              hipStream_t stream) {
    const float* pos = (const float*)d_in[0];
    const int* nj = (const int*)d_in[1];
    const int* nk = (const int*)d_in[2];
    float* out = (float*)d_out;

    // 4 rows per block (1 per wave): grid = B * N/4 = 2048 blocks, 256 threads.
    TriplesDistances_kernel<<<kB * (kN / 4), 256, 0, stream>>>(pos, nj, nk, out);
}